// Round 5
// baseline (130.228 us; speedup 1.0000x reference)
//
#include <hip/hip_runtime.h>
#include <math.h>

// SphereInterLoss R5: exact 10-NN, x-sorted, wave-autonomous quad-split.
//  prep_kernel: fused counting-rank (u64 keys, LDS-staged, quad j-split,
//               no atomics) + scatter of scaled sorted cloud
//               s4[r] = (-2x,-2y,-2z,|c|^2), srad[r] = radius.
//  knn_kernel : wave = 16 consecutive sorted queries x 4 lanes/query.
//               Each lane scans candidate residue (lane&3) of 64-chunks,
//               expanding outward from home; prune when trunc(gap^2) >
//               T = min(waveMax(k[9]), one-shot tight quad-merged bound).
//               Self excluded by index. Final 2-round shfl butterfly merge
//               (disjoint subsets -> no duplicate keys). No LDS/sync/atomics.
//  var_kernel : fused per-batch var(ddof=1) + mean, 1 block.

#define NB 8
#define NN 4096
#define NCH 64

__device__ __forceinline__ float med3f(float a, float b, float c) {
    return __builtin_amdgcn_fmed3f(a, b, c);
}

// branchless insert into ascending k[0..9], dropping the max
__device__ __forceinline__ void insert10(float k[10], float u) {
#pragma unroll
    for (int j = 9; j >= 1; --j) k[j] = med3f(k[j - 1], k[j], u);
    k[0] = fminf(k[0], u);
}

// ---------------- prep: rank by x + scatter scaled cloud ----------------
__global__ __launch_bounds__(256)
void prep_kernel(const float4* __restrict__ sp, float4* __restrict__ s4,
                 float* __restrict__ srad) {
    __shared__ unsigned long long keys[NN];     // 32 KB
    const int b = blockIdx.x >> 6, qt = blockIdx.x & 63;
    const int tid = threadIdx.x;
    const float4* spb = sp + ((size_t)b << 12);
    for (int j = tid; j < NN; j += 256) {
        unsigned u = __float_as_uint(spb[j].x);
        u = (u >> 31) ? ~u : (u | 0x80000000u);   // monotone map
        keys[j] = ((unsigned long long)u << 12) | (unsigned)j;
    }
    __syncthreads();
    const int e = (qt << 6) + (tid >> 2);
    const int part = tid & 3;
    const unsigned long long ke = keys[e];
    int cnt = 0;
#pragma unroll 4
    for (int i = 0; i < NN / 4; ++i)
        cnt += (int)(keys[(i << 2) | part] < ke);  // interleaved: no bank conflict
    cnt += __shfl_xor(cnt, 1, 64);
    cnt += __shfl_xor(cnt, 2, 64);
    if (part == 0) {
        float4 s = spb[e];
        float w = fmaf(s.x, s.x, fmaf(s.y, s.y, s.z * s.z));
        s4[(b << 12) + cnt] = make_float4(-2.f * s.x, -2.f * s.y, -2.f * s.z, w);
        srad[(b << 12) + cnt] = s.w;
    }
}

// ---------------- knn: wave-autonomous, quad-split queries ----------------
__global__ __launch_bounds__(256)
void knn_kernel(const float4* __restrict__ s4, const float* __restrict__ srad,
                float* __restrict__ td) {
    const int wid = (blockIdx.x << 2) | (threadIdx.x >> 6);   // 0..2047
    const int b = wid >> 8, w16 = wid & 255;
    const int lane = threadIdx.x & 63;
    const int sl = lane & 3, qi = lane >> 2;
    const float4* s4b = s4 + ((size_t)b << 12);
    const float* srb = srad + ((size_t)b << 12);

    const int qbase = w16 << 4;            // 16 consecutive sorted queries
    const int qs = qbase + qi;
    const float4 qraw = s4b[qs];
    const float qx = -0.5f * qraw.x, qy = -0.5f * qraw.y, qz = -0.5f * qraw.z;
    const float qw = qraw.w;
    const float xqlo = __shfl(qx, 0, 64);  // lane 0  -> query qbase
    const float xqhi = __shfl(qx, 63, 64); // lane 63 -> query qbase+15

    float k[10];
#pragma unroll
    for (int j = 0; j < 10; ++j) k[j] = __builtin_inff();

    const int c0 = qbase >> 6;             // all 16 queries share home chunk

    auto scan = [&](int c, bool home) {
        const int cb = c << 6;
#pragma unroll 4
        for (int i = 0; i < 16; ++i) {
            const int ci = cb + (i << 2) + sl;
            float4 cc = s4b[ci];
            float t  = qw + cc.w;
            float d2 = fmaf(qx, cc.x, fmaf(qy, cc.y, fmaf(qz, cc.z, t)));
            unsigned u = (__float_as_uint(d2) & 0xFFFFF000u) | (unsigned)ci;
            float uf = __uint_as_float(u);
            if (home && ci == qs) uf = __builtin_inff();   // exclude self
            insert10(k, uf);
        }
    };

    scan(c0, true);
    int cR = c0 + 1, cL = c0 - 1;
    bool goR = cR < NCH, goL = cL >= 0;
    float Tt = __builtin_inff();
    int nsc = 1, nxt = 5;

    while (goR || goL) {
        float T = k[9];
#pragma unroll
        for (int o = 32; o > 0; o >>= 1) T = fmaxf(T, __shfl_xor(T, o, 64));
        T = fminf(T, Tt);
        if (goR) {
            float xc = -0.5f * s4b[cR << 6].x;
            float gap = xc - xqhi;                       // >= 0 (sorted)
            float g2 = __uint_as_float(__float_as_uint(gap * gap) & 0xFFFFF000u);
            if (g2 > T) goR = false;
            else { scan(cR, false); ++cR; goR = cR < NCH; ++nsc; }
        }
        if (goL) {
            float xc = -0.5f * s4b[(cL << 6) + 63].x;
            float gap = xqlo - xc;                       // >= 0 (sorted)
            float g2 = __uint_as_float(__float_as_uint(gap * gap) & 0xFFFFF000u);
            if (g2 > T) goL = false;
            else { scan(cL, false); --cL; goL = cL >= 0; ++nsc; }
        }
        if (nsc >= nxt) {
            // one-shot tight bound: exact t10 of the scanned union, via a
            // COPY butterfly (keeps per-lane sets disjoint for final merge)
            float t[10];
#pragma unroll
            for (int j = 0; j < 10; ++j) t[j] = k[j];
#pragma unroll
            for (int r = 0; r < 2; ++r) {
                float f[10];
#pragma unroll
                for (int j = 0; j < 10; ++j) f[j] = __shfl_xor(t[j], 1 << r, 64);
#pragma unroll
                for (int j = 0; j < 10; ++j) insert10(t, f[j]);
            }
            float tt = t[9];
#pragma unroll
            for (int o = 32; o > 0; o >>= 1) tt = fmaxf(tt, __shfl_xor(tt, o, 64));
            Tt = tt;
            nxt = (nxt == 5) ? 13 : (1 << 30);
        }
    }

    // final quad merge: subsets disjoint -> exact top-10 of union
#pragma unroll
    for (int r = 0; r < 2; ++r) {
        float f[10];
#pragma unroll
        for (int j = 0; j < 10; ++j) f[j] = __shfl_xor(k[j], 1 << r, 64);
#pragma unroll
        for (int j = 0; j < 10; ++j) insert10(k, f[j]);
    }

    if (sl == 0) {
        const float rn = srb[qs];
        float best = __builtin_inff();
#pragma unroll
        for (int j = 0; j < 10; ++j) {
            int m = (int)(__float_as_uint(k[j]) & 0xFFFu);
            float4 cc = s4b[m];
            float dx = fmaf(0.5f, cc.x, qx);   // qx - orig_x(m), exact
            float dy = fmaf(0.5f, cc.y, qy);
            float dz = fmaf(0.5f, cc.z, qz);
            float dis = sqrtf(fmaf(dx, dx, fmaf(dy, dy, dz * dz)));
            best = fminf(best, dis - (rn + srb[m]));
        }
        td[(b << 12) + qs] = best;   // sorted order; variance perm-invariant
    }
}

// ---------------- fused per-batch variance (ddof=1) + mean ----------------
__global__ __launch_bounds__(512)
void var_kernel(const float* __restrict__ td, float* __restrict__ out) {
    __shared__ float part[NB];
    const int lane = threadIdx.x & 63, s = threadIdx.x >> 6;   // wave s: batch s
    const float4* x4 = (const float4*)(td + ((size_t)s << 12));

    float sum = 0.f;
#pragma unroll
    for (int i = 0; i < 16; ++i) {
        float4 v = x4[lane + (i << 6)];
        sum += (v.x + v.y) + (v.z + v.w);
    }
#pragma unroll
    for (int o = 32; o > 0; o >>= 1) sum += __shfl_xor(sum, o, 64);
    const float mu = sum / (float)NN;

    float ss = 0.f;
#pragma unroll
    for (int i = 0; i < 16; ++i) {
        float4 v = x4[lane + (i << 6)];
        float d0 = v.x - mu, d1 = v.y - mu, d2 = v.z - mu, d3 = v.w - mu;
        ss = fmaf(d0, d0, ss); ss = fmaf(d1, d1, ss);
        ss = fmaf(d2, d2, ss); ss = fmaf(d3, d3, ss);
    }
#pragma unroll
    for (int o = 32; o > 0; o >>= 1) ss += __shfl_xor(ss, o, 64);
    if (lane == 0) part[s] = ss / (float)(NN - 1);
    __syncthreads();
    if (threadIdx.x == 0) {
        float t = 0.f;
#pragma unroll
        for (int i = 0; i < NB; ++i) t += part[i];
        out[0] = t / (float)NB;
    }
}

extern "C" void kernel_launch(void* const* d_in, const int* in_sizes, int n_in,
                              void* d_out, int out_size, void* d_ws, size_t ws_size,
                              hipStream_t stream) {
    const float4* spheres = (const float4*)d_in[0];
    char* ws = (char*)d_ws;
    float4* s4   = (float4*)ws;                     // 512 KB
    float*  srad = (float*)(ws + 512 * 1024);       // 128 KB
    float*  td   = (float*)(ws + 640 * 1024);       // 128 KB
    float*  out  = (float*)d_out;

    prep_kernel<<<dim3(NB * 64), dim3(256), 0, stream>>>(spheres, s4, srad);
    knn_kernel<<<dim3(512), dim3(256), 0, stream>>>(s4, srad, td);
    var_kernel<<<dim3(1), dim3(512), 0, stream>>>(td, out);
}